// Round 4
// baseline (2966.216 us; speedup 1.0000x reference)
//
#include <hip/hip_runtime.h>
#include <hip/hip_bf16.h>
#include <type_traits>

// out = sum_b A_b @ (X @ W_b) + bias
// bucket = row>>6 (64 rows/bucket).
// 1) hist   : LDS-aggregated bucket histogram
// 2) scan   : exclusive scan of 8-padded counts, init global cursors
// 3) bscatter: LDS-binned scatter of packed 8B payloads -> bucket regions
//              (full 64B single-writer flushes; rare overflow goes direct)
// 4) gemm   : Y[n,512] = X @ W'  (fp32 compute, bf16 store, hop-major cols)
// 5) accum  : per-bucket LDS fp32 accumulate of val*Y[col,hop], + bias, write out

#define NBUK_MAX 800

// ---------------- GEMM (unchanged from round 3) ----------------
template <typename YT>
__global__ __launch_bounds__(256, 2) void gemm_kernel(
    const float* __restrict__ X, const float* __restrict__ W,
    YT* __restrict__ Y, int n_rows, int col0, int ystride)
{
  __shared__ float Xs[64][128];
  __shared__ float Ws[128][64];
  const int tid = threadIdx.x;
  const int row0 = blockIdx.y * 64;

  {
    const int lane = tid & 31;
    const int r = tid >> 5;
#pragma unroll
    for (int i = 0; i < 8; ++i) {
      const int rr = r + i * 8;
      const int gr = row0 + rr;
      float4 v = make_float4(0.f, 0.f, 0.f, 0.f);
      if (gr < n_rows) v = ((const float4*)(X + (size_t)gr * 128))[lane];
      ((float4*)&Xs[rr][0])[lane ^ ((rr >> 2) & 7)] = v;
    }
  }
  {
    const int gc0 = col0 + blockIdx.x * 64;
    const int b = gc0 >> 7;
    const int cc0 = gc0 & 127;
    const float* Wb = W + (size_t)b * 128 * 128 + cc0;
    const int lane16 = tid & 15;
    const int f = tid >> 4;
#pragma unroll
    for (int i = 0; i < 8; ++i) {
      const int ff = f + i * 16;
      const float4 v = *(const float4*)(Wb + (size_t)ff * 128 + lane16 * 4);
      ((float4*)&Ws[ff][0])[lane16] = v;
    }
  }
  __syncthreads();

  const int tx = tid & 15;
  const int ty = tid >> 4;
  float acc[4][4] = {};
#pragma unroll 2
  for (int f0 = 0; f0 < 128; f0 += 4) {
    float4 a[4];
#pragma unroll
    for (int i = 0; i < 4; ++i) {
      const int r = ty * 4 + i;
      a[i] = ((const float4*)&Xs[r][0])[(f0 >> 2) ^ ((r >> 2) & 7)];
    }
#pragma unroll
    for (int k = 0; k < 4; ++k) {
      const float4 b = *(const float4*)&Ws[f0 + k][tx * 4];
#pragma unroll
      for (int i = 0; i < 4; ++i) {
        const float av = (&a[i].x)[k];
        acc[i][0] = fmaf(av, b.x, acc[i][0]);
        acc[i][1] = fmaf(av, b.y, acc[i][1]);
        acc[i][2] = fmaf(av, b.z, acc[i][2]);
        acc[i][3] = fmaf(av, b.w, acc[i][3]);
      }
    }
  }
  const int yc = blockIdx.x * 64 + tx * 4;
#pragma unroll
  for (int i = 0; i < 4; ++i) {
    const int gr = row0 + ty * 4 + i;
    if (gr >= n_rows) continue;
    if constexpr (std::is_same<YT, float>::value) {
      *(float4*)(Y + (size_t)gr * ystride + yc) =
          make_float4(acc[i][0], acc[i][1], acc[i][2], acc[i][3]);
    } else {
      union { ushort4 u; __hip_bfloat16 h[4]; } p;
      p.h[0] = __float2bfloat16(acc[i][0]);
      p.h[1] = __float2bfloat16(acc[i][1]);
      p.h[2] = __float2bfloat16(acc[i][2]);
      p.h[3] = __float2bfloat16(acc[i][3]);
      *(ushort4*)(Y + (size_t)gr * ystride + yc) = p.u;
    }
  }
}

// ---------------- bucket histogram (LDS aggregated) ----------------
__global__ __launch_bounds__(256) void hist_kernel(
    const int* __restrict__ rows, int* __restrict__ cnt, unsigned ntot, int nbuk)
{
  __shared__ int lcnt[NBUK_MAX];
  for (int i = threadIdx.x; i < nbuk; i += 256) lcnt[i] = 0;
  __syncthreads();
  for (unsigned e = blockIdx.x * 256u + threadIdx.x; e < ntot; e += gridDim.x * 256u)
    atomicAdd(&lcnt[((unsigned)rows[e]) >> 6], 1);
  __syncthreads();
  for (int i = threadIdx.x; i < nbuk; i += 256)
    if (lcnt[i]) atomicAdd(&cnt[i], lcnt[i]);
}

// ---------------- scan of 8-padded counts; init cursors ----------------
__global__ __launch_bounds__(1024) void scan_kernel(
    const int* __restrict__ cnt, int* __restrict__ pstart,
    int* __restrict__ gcur, int nbuk)
{
  __shared__ int buf[1024];
  const int t = threadIdx.x;
  const int v = (t < nbuk) ? ((cnt[t] + 7) & ~7) : 0;
  buf[t] = v;
  __syncthreads();
  for (int off = 1; off < 1024; off <<= 1) {
    const int add = (t >= off) ? buf[t - off] : 0;
    __syncthreads();
    buf[t] += add;
    __syncthreads();
  }
  if (t < nbuk) {
    const int s = buf[t] - v;   // exclusive, 8-aligned
    pstart[t] = s;
    gcur[t] = s;
  }
}

// ---------------- LDS-binned scatter ----------------
// payload: x = row<<16 | col ; y = hop<<30 | val_bits (val in [0,1) => 30 bits, exact)
__global__ __launch_bounds__(256) void bscatter_kernel(
    const int* __restrict__ rows, const int* __restrict__ cols,
    const float* __restrict__ vals, int* __restrict__ gcur,
    uint2* __restrict__ staged, unsigned ntot, unsigned epb, int nbuk)
{
  __shared__ int bcnt[NBUK_MAX];
  __shared__ uint2 bins[NBUK_MAX * 8];
  for (int i = threadIdx.x; i < nbuk; i += 256) bcnt[i] = 0;
  __syncthreads();

  const unsigned chunk = (ntot + gridDim.x - 1) / gridDim.x;
  const unsigned beg = blockIdx.x * chunk;
  const unsigned end = (beg + chunk < ntot) ? (beg + chunk) : ntot;

  for (unsigned base = beg; base < end; base += 512) {
#pragma unroll
    for (int k = 0; k < 2; ++k) {
      const unsigned e = base + (unsigned)k * 256u + threadIdx.x;
      if (e < end) {
        const unsigned r = (unsigned)rows[e];
        const unsigned c = (unsigned)cols[e];
        const unsigned hop = (e >= 2u * epb) ? ((e >= 3u * epb) ? 3u : 2u)
                                             : ((e >= epb) ? 1u : 0u);
        const uint2 pay = make_uint2((r << 16) | c,
                                     (hop << 30) | __float_as_uint(vals[e]));
        const int bk = (int)(r >> 6);
        const int p = atomicAdd(&bcnt[bk], 1);
        if (p < 8) bins[bk * 8 + p] = pay;
        else {  // rare ring overflow: direct scattered write
          const int gp = atomicAdd(&gcur[bk], 1);
          staged[gp] = pay;
        }
      }
    }
    __syncthreads();
    for (int bk = threadIdx.x; bk < nbuk; bk += 256) {
      if (bcnt[bk] >= 8) {      // flush one full 64B chunk, single writer
        const int gp = atomicAdd(&gcur[bk], 8);
        uint2* dst = staged + gp;
#pragma unroll
        for (int q = 0; q < 8; ++q) dst[q] = bins[bk * 8 + q];
        bcnt[bk] = 0;
      }
    }
    __syncthreads();
  }
  // drain leftovers
  for (int bk = threadIdx.x; bk < nbuk; bk += 256) {
    const int c = bcnt[bk];
    if (c > 0) {
      const int gp = atomicAdd(&gcur[bk], c);
      for (int q = 0; q < c; ++q) staged[gp + q] = bins[bk * 8 + q];
    }
  }
}

// ---------------- per-bucket accumulate ----------------
__global__ __launch_bounds__(256) void accum_kernel(
    const int* __restrict__ cnt, const int* __restrict__ pstart,
    const uint2* __restrict__ staged, const __hip_bfloat16* __restrict__ Y,
    const float* __restrict__ bias, float* __restrict__ out, int n)
{
  __shared__ float acc[64 * 128];   // 32 KiB
  const int bk = blockIdx.x;
  const float4 z = make_float4(0.f, 0.f, 0.f, 0.f);
  for (int i = threadIdx.x; i < 64 * 32; i += 256) ((float4*)acc)[i] = z;
  __syncthreads();

  const int js = pstart[bk];
  const int je = js + cnt[bk];
  const int lane = threadIdx.x & 63;
  const int w = threadIdx.x >> 6;

  auto body = [&](int j) {
    const uint2 p = staged[j];
    const unsigned rl = (p.x >> 16) & 63u;
    const unsigned col = p.x & 0xFFFFu;
    const unsigned hop = p.y >> 30;
    const float v = __uint_as_float(p.y & 0x3FFFFFFFu);
    const __hip_bfloat162 y2 =
        *(const __hip_bfloat162*)(Y + (size_t)col * 512 + hop * 128 + lane * 2);
    atomicAdd(&acc[rl * 128 + lane * 2 + 0], v * __low2float(y2));
    atomicAdd(&acc[rl * 128 + lane * 2 + 1], v * __high2float(y2));
  };

  int j = js + w;
  for (; j + 12 < je; j += 16) {   // 4 edges in flight per wave
    body(j); body(j + 4); body(j + 8); body(j + 12);
  }
  for (; j < je; j += 4) body(j);
  __syncthreads();

  const int gr0 = bk * 64;
  for (int i = threadIdx.x; i < 64 * 32; i += 256) {
    const int rl = i >> 5, c4 = i & 31;
    const int gr = gr0 + rl;
    if (gr < n) {
      const float4 a = ((const float4*)acc)[i];
      const float4 b = ((const float4*)bias)[c4];
      *(float4*)(out + (size_t)gr * 128 + c4 * 4) =
          make_float4(a.x + b.x, a.y + b.y, a.z + b.z, a.w + b.w);
    }
  }
}

// ---------------- fallback (atomic path) ----------------
__global__ __launch_bounds__(256) void init_out_kernel(
    float* __restrict__ out, const float* __restrict__ bias, int nquads)
{
  int i = blockIdx.x * blockDim.x + threadIdx.x;
  if (i >= nquads) return;
  const float4 b = ((const float4*)bias)[i & 31];
  ((float4*)out)[i] = b;
}

__global__ __launch_bounds__(256) void scatter_kernel(
    const int* __restrict__ rows, const int* __restrict__ cols,
    const float* __restrict__ vals, const float* __restrict__ Y,
    int ystride, int yblk, unsigned epb, unsigned ntot,
    float* __restrict__ out)
{
  const unsigned e = blockIdx.x * 8u + (threadIdx.x >> 5);
  if (e >= ntot) return;
  const int lane = threadIdx.x & 31;
  const int row = rows[e];
  const int col = cols[e];
  const float v = vals[e];
  const unsigned b = e / epb;
  const float4 y = *(const float4*)(Y + (size_t)col * ystride + (size_t)b * yblk + lane * 4);
  float* o = out + (size_t)row * 128 + lane * 4;
  atomicAdd(o + 0, v * y.x);
  atomicAdd(o + 1, v * y.y);
  atomicAdd(o + 2, v * y.z);
  atomicAdd(o + 3, v * y.w);
}

extern "C" void kernel_launch(void* const* d_in, const int* in_sizes, int n_in,
                              void* d_out, int out_size, void* d_ws, size_t ws_size,
                              hipStream_t stream) {
  const float* X    = (const float*)d_in[0];
  const int*   rows = (const int*)d_in[1];
  const int*   cols = (const int*)d_in[2];
  const float* vals = (const float*)d_in[3];
  const float* W    = (const float*)d_in[4];
  const float* bias = (const float*)d_in[5];
  float* out = (float*)d_out;

  const int n = out_size / 128;                 // 50000
  const unsigned ntot = (unsigned)in_sizes[1];  // 3.2M flat
  const unsigned epb = ntot / 4u;
  const int nbuk = (n + 63) >> 6;               // 782

  auto align = [](size_t x) { return (x + 255) & ~(size_t)255; };
  const size_t sz_cnt    = align((size_t)nbuk * 4);
  const size_t sz_pstart = align((size_t)nbuk * 4);
  const size_t sz_gcur   = align((size_t)nbuk * 4);
  const size_t sz_staged = align(((size_t)ntot + 8u * (size_t)nbuk) * 8);
  const size_t sz_y_bf16 = align((size_t)n * 512 * 2);
  const size_t meta = sz_cnt + sz_pstart + sz_gcur + sz_staged;

  char* ws = (char*)d_ws;
  int*   cnt    = (int*)(ws);
  int*   pstart = (int*)(ws + sz_cnt);
  int*   gcur   = (int*)(ws + sz_cnt + sz_pstart);
  uint2* staged = (uint2*)(ws + sz_cnt + sz_pstart + sz_gcur);
  __hip_bfloat16* Y = (__hip_bfloat16*)(ws + meta);

  const bool fast_ok = (n <= 65535) && (nbuk <= NBUK_MAX) && (ntot % 4u == 0u) &&
                       (in_sizes[0] == n * 128) &&
                       (ws_size >= meta + sz_y_bf16);

  if (fast_ok) {
    hipMemsetAsync(cnt, 0, (size_t)nbuk * 4, stream);
    hist_kernel<<<dim3(256), dim3(256), 0, stream>>>(rows, cnt, ntot, nbuk);
    scan_kernel<<<dim3(1), dim3(1024), 0, stream>>>(cnt, pstart, gcur, nbuk);
    bscatter_kernel<<<dim3(128), dim3(256), 0, stream>>>(
        rows, cols, vals, gcur, staged, ntot, epb, nbuk);
    dim3 g(512 / 64, (n + 63) / 64);
    gemm_kernel<__hip_bfloat16><<<g, dim3(256), 0, stream>>>(X, W, Y, n, 0, 512);
    accum_kernel<<<dim3(nbuk), dim3(256), 0, stream>>>(
        cnt, pstart, staged, Y, bias, out, n);
    return;
  }

  // Fallback: atomic path
  {
    const int nquads = n * 32;
    init_out_kernel<<<dim3((nquads + 255) / 256), dim3(256), 0, stream>>>(out, bias, nquads);
    float* Yf = (float*)d_ws;
    const size_t need_fused = (size_t)n * 512 * sizeof(float);
    if (ws_size >= need_fused) {
      dim3 g(512 / 64, (n + 63) / 64);
      gemm_kernel<float><<<g, dim3(256), 0, stream>>>(X, W, Yf, n, 0, 512);
      const unsigned nblk = (ntot + 7) / 8;
      scatter_kernel<<<dim3(nblk), dim3(256), 0, stream>>>(
          rows, cols, vals, Yf, 512, 128, epb, ntot, out);
    } else {
      for (unsigned b = 0; b < 4; ++b) {
        dim3 g(128 / 64, (n + 63) / 64);
        gemm_kernel<float><<<g, dim3(256), 0, stream>>>(X, W, Yf, n, (int)(b * 128), 128);
        const unsigned nblk = (epb + 7) / 8;
        scatter_kernel<<<dim3(nblk), dim3(256), 0, stream>>>(
            rows + (size_t)b * epb, cols + (size_t)b * epb, vals + (size_t)b * epb,
            Yf, 128, 0, epb, epb, out);
      }
    }
  }
}

// Round 5
// 447.196 us; speedup vs baseline: 6.6329x; 6.6329x over previous
//
#include <hip/hip_runtime.h>
#include <hip/hip_bf16.h>
#include <type_traits>

// out = sum_b A_b @ (X @ W_b) + bias
// 1) hist    : LDS-aggregated bucket histogram (bucket = row>>6)
// 2) scan2   : excl scans (8-padded -> staged regions, exact -> ep regions)
// 3) bscatter: LDS-binned scatter, single-writer 64B flushes -> staged
// 4) reorder : per-bucket LDS counting sort -> exact row-CSR ep + row_start
// 5) gemm    : Y[n,512] = X @ W' (fp32 compute, bf16 store, hop-major cols)
// 6) gather  : one wave per row, register accumulate, coalesced Y reads

#define NBUK_MAX 800
#define RCAP 6144   // reorder LDS capacity (edges per bucket); mean ~4096

// ---------------- GEMM ----------------
template <typename YT>
__global__ __launch_bounds__(256, 2) void gemm_kernel(
    const float* __restrict__ X, const float* __restrict__ W,
    YT* __restrict__ Y, int n_rows, int col0, int ystride)
{
  __shared__ float Xs[64][128];
  __shared__ float Ws[128][64];
  const int tid = threadIdx.x;
  const int row0 = blockIdx.y * 64;

  {
    const int lane = tid & 31;
    const int r = tid >> 5;
#pragma unroll
    for (int i = 0; i < 8; ++i) {
      const int rr = r + i * 8;
      const int gr = row0 + rr;
      float4 v = make_float4(0.f, 0.f, 0.f, 0.f);
      if (gr < n_rows) v = ((const float4*)(X + (size_t)gr * 128))[lane];
      ((float4*)&Xs[rr][0])[lane ^ ((rr >> 2) & 7)] = v;
    }
  }
  {
    const int gc0 = col0 + blockIdx.x * 64;
    const int b = gc0 >> 7;
    const int cc0 = gc0 & 127;
    const float* Wb = W + (size_t)b * 128 * 128 + cc0;
    const int lane16 = tid & 15;
    const int f = tid >> 4;
#pragma unroll
    for (int i = 0; i < 8; ++i) {
      const int ff = f + i * 16;
      const float4 v = *(const float4*)(Wb + (size_t)ff * 128 + lane16 * 4);
      ((float4*)&Ws[ff][0])[lane16] = v;
    }
  }
  __syncthreads();

  const int tx = tid & 15;
  const int ty = tid >> 4;
  float acc[4][4] = {};
#pragma unroll 2
  for (int f0 = 0; f0 < 128; f0 += 4) {
    float4 a[4];
#pragma unroll
    for (int i = 0; i < 4; ++i) {
      const int r = ty * 4 + i;
      a[i] = ((const float4*)&Xs[r][0])[(f0 >> 2) ^ ((r >> 2) & 7)];
    }
#pragma unroll
    for (int k = 0; k < 4; ++k) {
      const float4 b = *(const float4*)&Ws[f0 + k][tx * 4];
#pragma unroll
      for (int i = 0; i < 4; ++i) {
        const float av = (&a[i].x)[k];
        acc[i][0] = fmaf(av, b.x, acc[i][0]);
        acc[i][1] = fmaf(av, b.y, acc[i][1]);
        acc[i][2] = fmaf(av, b.z, acc[i][2]);
        acc[i][3] = fmaf(av, b.w, acc[i][3]);
      }
    }
  }
  const int yc = blockIdx.x * 64 + tx * 4;
#pragma unroll
  for (int i = 0; i < 4; ++i) {
    const int gr = row0 + ty * 4 + i;
    if (gr >= n_rows) continue;
    if constexpr (std::is_same<YT, float>::value) {
      *(float4*)(Y + (size_t)gr * ystride + yc) =
          make_float4(acc[i][0], acc[i][1], acc[i][2], acc[i][3]);
    } else {
      union { ushort4 u; __hip_bfloat16 h[4]; } p;
      p.h[0] = __float2bfloat16(acc[i][0]);
      p.h[1] = __float2bfloat16(acc[i][1]);
      p.h[2] = __float2bfloat16(acc[i][2]);
      p.h[3] = __float2bfloat16(acc[i][3]);
      *(ushort4*)(Y + (size_t)gr * ystride + yc) = p.u;
    }
  }
}

// ---------------- bucket histogram ----------------
__global__ __launch_bounds__(256) void hist_kernel(
    const int* __restrict__ rows, int* __restrict__ cnt, unsigned ntot, int nbuk)
{
  __shared__ int lcnt[NBUK_MAX];
  for (int i = threadIdx.x; i < nbuk; i += 256) lcnt[i] = 0;
  __syncthreads();
  for (unsigned e = blockIdx.x * 256u + threadIdx.x; e < ntot; e += gridDim.x * 256u)
    atomicAdd(&lcnt[((unsigned)rows[e]) >> 6], 1);
  __syncthreads();
  for (int i = threadIdx.x; i < nbuk; i += 256)
    if (lcnt[i]) atomicAdd(&cnt[i], lcnt[i]);
}

// ---------------- dual scans ----------------
__global__ __launch_bounds__(1024) void scan2_kernel(
    const int* __restrict__ cnt, int* __restrict__ pstart8,
    int* __restrict__ pstartX, int* __restrict__ gcur,
    int* __restrict__ row_start, int nbuk, int n, unsigned ntot)
{
  __shared__ int buf[1024];
  const int t = threadIdx.x;
  const int c = (t < nbuk) ? cnt[t] : 0;
  int v = (c + 7) & ~7;                 // padded (staged regions, 64B aligned)
  buf[t] = v;
  __syncthreads();
  for (int off = 1; off < 1024; off <<= 1) {
    const int add = (t >= off) ? buf[t - off] : 0;
    __syncthreads();
    buf[t] += add;
    __syncthreads();
  }
  if (t < nbuk) { pstart8[t] = buf[t] - v; gcur[t] = buf[t] - v; }
  __syncthreads();
  buf[t] = c;                           // exact (ep regions)
  __syncthreads();
  for (int off = 1; off < 1024; off <<= 1) {
    const int add = (t >= off) ? buf[t - off] : 0;
    __syncthreads();
    buf[t] += add;
    __syncthreads();
  }
  if (t < nbuk) pstartX[t] = buf[t] - c;
  if (t == 0) row_start[n] = (int)ntot;
}

// ---------------- LDS-binned scatter ----------------
// payload: x = row<<16 | col ; y = hop<<30 | val_bits (val in [0,1) => 30 bits)
__global__ __launch_bounds__(256) void bscatter_kernel(
    const int* __restrict__ rows, const int* __restrict__ cols,
    const float* __restrict__ vals, int* __restrict__ gcur,
    uint2* __restrict__ staged, unsigned ntot, unsigned epb, int nbuk)
{
  __shared__ int bcnt[NBUK_MAX];
  __shared__ uint2 bins[NBUK_MAX * 8];
  for (int i = threadIdx.x; i < nbuk; i += 256) bcnt[i] = 0;
  __syncthreads();

  const unsigned chunk = (ntot + gridDim.x - 1) / gridDim.x;
  const unsigned beg = blockIdx.x * chunk;
  const unsigned end = (beg + chunk < ntot) ? (beg + chunk) : ntot;

  for (unsigned base = beg; base < end; base += 512) {
#pragma unroll
    for (int k = 0; k < 2; ++k) {
      const unsigned e = base + (unsigned)k * 256u + threadIdx.x;
      if (e < end) {
        const unsigned r = (unsigned)rows[e];
        const unsigned c = (unsigned)cols[e];
        const unsigned hop = (e >= 2u * epb) ? ((e >= 3u * epb) ? 3u : 2u)
                                             : ((e >= epb) ? 1u : 0u);
        const uint2 pay = make_uint2((r << 16) | c,
                                     (hop << 30) | __float_as_uint(vals[e]));
        const int bk = (int)(r >> 6);
        const int p = atomicAdd(&bcnt[bk], 1);
        if (p < 8) bins[bk * 8 + p] = pay;
        else {
          const int gp = atomicAdd(&gcur[bk], 1);
          staged[gp] = pay;
        }
      }
    }
    __syncthreads();
    for (int bk = threadIdx.x; bk < nbuk; bk += 256) {
      if (bcnt[bk] >= 8) {
        const int gp = atomicAdd(&gcur[bk], 8);
        uint2* dst = staged + gp;
#pragma unroll
        for (int q = 0; q < 8; ++q) dst[q] = bins[bk * 8 + q];
        bcnt[bk] = 0;
      }
    }
    __syncthreads();
  }
  for (int bk = threadIdx.x; bk < nbuk; bk += 256) {
    const int c = bcnt[bk];
    if (c > 0) {
      const int gp = atomicAdd(&gcur[bk], c);
      for (int q = 0; q < c; ++q) staged[gp + q] = bins[bk * 8 + q];
    }
  }
}

// ---------------- per-bucket counting sort -> exact CSR ----------------
__global__ __launch_bounds__(256) void reorder_kernel(
    const int* __restrict__ cnt, const int* __restrict__ pstart8,
    const int* __restrict__ pstartX, const uint2* __restrict__ staged,
    uint2* __restrict__ ep, int* __restrict__ row_start, int n)
{
  __shared__ int lcnt[64], lstart[64], lcur[64];
  __shared__ uint2 lbuf[RCAP];
  const int bk = blockIdx.x;
  const int c = cnt[bk];
  const int s8 = pstart8[bk];
  const int sx = pstartX[bk];

  if (threadIdx.x < 64) lcnt[threadIdx.x] = 0;
  __syncthreads();
  for (int j = threadIdx.x; j < c; j += 256)
    atomicAdd(&lcnt[(staged[s8 + j].x >> 16) & 63u], 1);
  __syncthreads();
  if (threadIdx.x == 0) {
    int a = 0;
    for (int i = 0; i < 64; ++i) { lstart[i] = a; lcur[i] = a; a += lcnt[i]; }
  }
  __syncthreads();
  if (threadIdx.x < 64) {
    const int gr = bk * 64 + threadIdx.x;
    if (gr < n) row_start[gr] = sx + lstart[threadIdx.x];
  }
  if (c <= RCAP) {
    for (int j = threadIdx.x; j < c; j += 256) {
      const uint2 p = staged[s8 + j];
      const unsigned rl = (p.x >> 16) & 63u;
      const int pos = atomicAdd(&lcur[rl], 1);
      lbuf[pos] = make_uint2((p.x & 0xFFFFu) * 512u + (p.y >> 30) * 128u,
                             p.y & 0x3FFFFFFFu);
    }
    __syncthreads();
    for (int j = threadIdx.x; j < c; j += 256) ep[sx + j] = lbuf[j];
  } else {  // pathological skew fallback: scattered but correct
    for (int j = threadIdx.x; j < c; j += 256) {
      const uint2 p = staged[s8 + j];
      const unsigned rl = (p.x >> 16) & 63u;
      const int pos = atomicAdd(&lcur[rl], 1);
      ep[sx + pos] = make_uint2((p.x & 0xFFFFu) * 512u + (p.y >> 30) * 128u,
                                p.y & 0x3FFFFFFFu);
    }
  }
}

// ---------------- gather: one wave per row ----------------
__global__ __launch_bounds__(256) void gather_kernel(
    const int* __restrict__ row_start, const uint2* __restrict__ ep,
    const __hip_bfloat16* __restrict__ Y, const float* __restrict__ bias,
    float* __restrict__ out, int n)
{
  const int wid = (int)((blockIdx.x * 256u + threadIdx.x) >> 6);
  if (wid >= n) return;
  const int lane = threadIdx.x & 63;
  const int js = row_start[wid];
  const int je = row_start[wid + 1];
  float ax = 0.f, ay = 0.f;

  auto ld = [&](uint2 p) -> float2 {
    const __hip_bfloat162 h = *(const __hip_bfloat162*)(Y + (size_t)p.x + lane * 2);
    const float v = __uint_as_float(p.y);
    return make_float2(v * __low2float(h), v * __high2float(h));
  };

  int j = js;
  for (; j + 3 < je; j += 4) {
    const uint2 p0 = ep[j], p1 = ep[j + 1], p2 = ep[j + 2], p3 = ep[j + 3];
    const float2 t0 = ld(p0), t1 = ld(p1), t2 = ld(p2), t3 = ld(p3);
    ax += (t0.x + t1.x) + (t2.x + t3.x);
    ay += (t0.y + t1.y) + (t2.y + t3.y);
  }
  for (; j < je; ++j) {
    const float2 t = ld(ep[j]);
    ax += t.x; ay += t.y;
  }
  const float2 bb = *(const float2*)(bias + lane * 2);
  *(float2*)(out + (size_t)wid * 128 + lane * 2) = make_float2(ax + bb.x, ay + bb.y);
}

// ---------------- fallback (atomic path) ----------------
__global__ __launch_bounds__(256) void init_out_kernel(
    float* __restrict__ out, const float* __restrict__ bias, int nquads)
{
  int i = blockIdx.x * blockDim.x + threadIdx.x;
  if (i >= nquads) return;
  const float4 b = ((const float4*)bias)[i & 31];
  ((float4*)out)[i] = b;
}

__global__ __launch_bounds__(256) void scatter_kernel(
    const int* __restrict__ rows, const int* __restrict__ cols,
    const float* __restrict__ vals, const float* __restrict__ Y,
    int ystride, int yblk, unsigned epb, unsigned ntot,
    float* __restrict__ out)
{
  const unsigned e = blockIdx.x * 8u + (threadIdx.x >> 5);
  if (e >= ntot) return;
  const int lane = threadIdx.x & 31;
  const int row = rows[e];
  const int col = cols[e];
  const float v = vals[e];
  const unsigned b = e / epb;
  const float4 y = *(const float4*)(Y + (size_t)col * ystride + (size_t)b * yblk + lane * 4);
  float* o = out + (size_t)row * 128 + lane * 4;
  atomicAdd(o + 0, v * y.x);
  atomicAdd(o + 1, v * y.y);
  atomicAdd(o + 2, v * y.z);
  atomicAdd(o + 3, v * y.w);
}

extern "C" void kernel_launch(void* const* d_in, const int* in_sizes, int n_in,
                              void* d_out, int out_size, void* d_ws, size_t ws_size,
                              hipStream_t stream) {
  const float* X    = (const float*)d_in[0];
  const int*   rows = (const int*)d_in[1];
  const int*   cols = (const int*)d_in[2];
  const float* vals = (const float*)d_in[3];
  const float* W    = (const float*)d_in[4];
  const float* bias = (const float*)d_in[5];
  float* out = (float*)d_out;

  const int n = out_size / 128;                 // 50000
  const unsigned ntot = (unsigned)in_sizes[1];  // 3.2M flat
  const unsigned epb = ntot / 4u;
  const int nbuk = (n + 63) >> 6;               // 782

  auto align = [](size_t x) { return (x + 255) & ~(size_t)255; };
  const size_t sz_cnt    = align((size_t)nbuk * 4);
  const size_t sz_p8     = align((size_t)nbuk * 4);
  const size_t sz_px     = align((size_t)nbuk * 4);
  const size_t sz_gcur   = align((size_t)nbuk * 4);
  const size_t sz_rstart = align((size_t)(n + 1) * 4);
  const size_t sz_staged = align(((size_t)ntot + 8u * (size_t)nbuk) * 8);
  const size_t sz_ep     = align((size_t)ntot * 8);
  const size_t sz_y_bf16 = align((size_t)n * 512 * 2);
  const size_t meta = sz_cnt + sz_p8 + sz_px + sz_gcur + sz_rstart + sz_staged + sz_ep;

  char* ws = (char*)d_ws;
  int*   cnt       = (int*)(ws);
  int*   pstart8   = (int*)(ws + sz_cnt);
  int*   pstartX   = (int*)(ws + sz_cnt + sz_p8);
  int*   gcur      = (int*)(ws + sz_cnt + sz_p8 + sz_px);
  int*   row_start = (int*)(ws + sz_cnt + sz_p8 + sz_px + sz_gcur);
  uint2* staged    = (uint2*)(ws + sz_cnt + sz_p8 + sz_px + sz_gcur + sz_rstart);
  uint2* ep        = (uint2*)(ws + sz_cnt + sz_p8 + sz_px + sz_gcur + sz_rstart + sz_staged);
  __hip_bfloat16* Y = (__hip_bfloat16*)(ws + meta);

  const bool fast_ok = (n <= 65535) && (nbuk <= NBUK_MAX) && (nbuk <= 1024) &&
                       (ntot % 4u == 0u) && (in_sizes[0] == n * 128) &&
                       (ws_size >= meta + sz_y_bf16);

  if (fast_ok) {
    hipMemsetAsync(cnt, 0, (size_t)nbuk * 4, stream);
    hist_kernel<<<dim3(256), dim3(256), 0, stream>>>(rows, cnt, ntot, nbuk);
    scan2_kernel<<<dim3(1), dim3(1024), 0, stream>>>(
        cnt, pstart8, pstartX, gcur, row_start, nbuk, n, ntot);
    bscatter_kernel<<<dim3(128), dim3(256), 0, stream>>>(
        rows, cols, vals, gcur, staged, ntot, epb, nbuk);
    reorder_kernel<<<dim3(nbuk), dim3(256), 0, stream>>>(
        cnt, pstart8, pstartX, staged, ep, row_start, n);
    dim3 g(512 / 64, (n + 63) / 64);
    gemm_kernel<__hip_bfloat16><<<g, dim3(256), 0, stream>>>(X, W, Y, n, 0, 512);
    const unsigned gblk = (unsigned)((n + 3) / 4);
    gather_kernel<<<dim3(gblk), dim3(256), 0, stream>>>(
        row_start, ep, Y, bias, out, n);
    return;
  }

  // Fallback: atomic path
  {
    const int nquads = n * 32;
    init_out_kernel<<<dim3((nquads + 255) / 256), dim3(256), 0, stream>>>(out, bias, nquads);
    float* Yf = (float*)d_ws;
    const size_t need_fused = (size_t)n * 512 * sizeof(float);
    if (ws_size >= need_fused) {
      dim3 g(512 / 64, (n + 63) / 64);
      gemm_kernel<float><<<g, dim3(256), 0, stream>>>(X, W, Yf, n, 0, 512);
      const unsigned nblk = (ntot + 7) / 8;
      scatter_kernel<<<dim3(nblk), dim3(256), 0, stream>>>(
          rows, cols, vals, Yf, 512, 128, epb, ntot, out);
    } else {
      for (unsigned b = 0; b < 4; ++b) {
        dim3 g(128 / 64, (n + 63) / 64);
        gemm_kernel<float><<<g, dim3(256), 0, stream>>>(X, W, Yf, n, (int)(b * 128), 128);
        const unsigned nblk = (epb + 7) / 8;
        scatter_kernel<<<dim3(nblk), dim3(256), 0, stream>>>(
            rows + (size_t)b * epb, cols + (size_t)b * epb, vals + (size_t)b * epb,
            Yf, 128, 0, epb, epb, out);
      }
    }
  }
}